// Round 1
// baseline (1560.486 us; speedup 1.0000x reference)
//
#include <hip/hip_runtime.h>
#include <hip/hip_bf16.h>

#define DOUT 64
#define DIN 128
#define NEG_SLOPE 0.2f
#define EPSV 1e-10f
#define LDA 136   // 128 + 8 bf16 pad: breaks 16-row bank aliasing (2-way max, free)

typedef __attribute__((ext_vector_type(8))) __bf16 bf16x8;
typedef __attribute__((ext_vector_type(8))) unsigned short ushortx8;
typedef __attribute__((ext_vector_type(4))) float floatx4;

__device__ __forceinline__ unsigned short f32_to_bf16_rne(float f) {
    unsigned int u = __float_as_uint(f);
    u += 0x7fffu + ((u >> 16) & 1u);
    return (unsigned short)(u >> 16);
}

// ---------------------------------------------------------------------------
// Kernel B: Wh = x @ W via bf16 MFMA (f32 accum), fused epilogue computing
// s_src[row] = Wh[row]·a[0:64], s_tgt[row] = Wh[row]·a[64:128].
// Block = 256 threads = 4 waves; block tile = 64 rows x 64 cols; K = 128.
// ---------------------------------------------------------------------------
__global__ __launch_bounds__(256) void gat_gemm_scores(
    const float* __restrict__ x, const float* __restrict__ W,
    const float* __restrict__ a, float* __restrict__ Wh,
    float* __restrict__ ssrc, float* __restrict__ stgt, int N)
{
    __shared__ unsigned short A_sh[64 * LDA];  // x tile, [row][k] bf16
    __shared__ unsigned short B_sh[64 * LDA];  // W^T,    [n][k]   bf16

    const int tid = threadIdx.x;
    const int rowbase = blockIdx.x * 64;

    // Stage W^T (128x64 f32 -> [n][k] bf16). Coalesced reads, scattered LDS writes.
    for (int idx = tid; idx < DIN * DOUT; idx += 256) {
        int k = idx >> 6, n = idx & 63;
        B_sh[n * LDA + k] = f32_to_bf16_rne(W[idx]);
    }
    // Stage A: 64 rows x 128 k, float4 coalesced, cvt to bf16.
    for (int it = 0; it < 8; ++it) {
        int flat = it * 1024 + tid * 4;
        int row = flat >> 7, k = flat & 127;
        int grow = rowbase + row;
        float4 v = make_float4(0.f, 0.f, 0.f, 0.f);
        if (grow < N) v = *(const float4*)&x[(size_t)grow * DIN + k];
        ushort4 u;
        u.x = f32_to_bf16_rne(v.x); u.y = f32_to_bf16_rne(v.y);
        u.z = f32_to_bf16_rne(v.z); u.w = f32_to_bf16_rne(v.w);
        *(ushort4*)&A_sh[row * LDA + k] = u;
    }
    __syncthreads();

    const int lane = tid & 63;
    const int wv   = tid >> 6;        // wave id: rows [wv*16, wv*16+16)
    const int c16  = lane & 15;
    const int quad = lane >> 4;

    floatx4 acc[4] = {floatx4{0,0,0,0}, floatx4{0,0,0,0},
                      floatx4{0,0,0,0}, floatx4{0,0,0,0}};

    const int arow = (wv * 16 + c16) * LDA;
    #pragma unroll
    for (int kk = 0; kk < 4; ++kk) {
        const int koff = kk * 32 + quad * 8;
        bf16x8 af = __builtin_bit_cast(bf16x8, *(const ushortx8*)&A_sh[arow + koff]);
        #pragma unroll
        for (int nt = 0; nt < 4; ++nt) {
            bf16x8 bf = __builtin_bit_cast(bf16x8,
                           *(const ushortx8*)&B_sh[(nt * 16 + c16) * LDA + koff]);
            acc[nt] = __builtin_amdgcn_mfma_f32_16x16x32_bf16(af, bf, acc[nt], 0, 0, 0);
        }
    }

    // Epilogue: C/D layout col = lane&15 (+nt*16), row = quad*4 + reg.
    float asrc_v[4], atgt_v[4];
    #pragma unroll
    for (int nt = 0; nt < 4; ++nt) {
        asrc_v[nt] = a[nt * 16 + c16];
        atgt_v[nt] = a[64 + nt * 16 + c16];
    }
    const int rbase = rowbase + wv * 16 + quad * 4;
    #pragma unroll
    for (int r = 0; r < 4; ++r) {
        int row = rbase + r;
        if (row < N) {
            #pragma unroll
            for (int nt = 0; nt < 4; ++nt)
                Wh[(size_t)row * DOUT + nt * 16 + c16] = acc[nt][r];
        }
    }
    #pragma unroll
    for (int r = 0; r < 4; ++r) {
        float ps = 0.f, pt = 0.f;
        #pragma unroll
        for (int nt = 0; nt < 4; ++nt) {
            ps += acc[nt][r] * asrc_v[nt];
            pt += acc[nt][r] * atgt_v[nt];
        }
        // reduce across the 16 lanes (same quad) holding cols 0..63
        #pragma unroll
        for (int m = 1; m < 16; m <<= 1) {
            ps += __shfl_xor(ps, m);
            pt += __shfl_xor(pt, m);
        }
        if (c16 == 0) {
            int row = rbase + r;
            if (row < N) { ssrc[row] = ps; stgt[row] = pt; }
        }
    }
}

// ---------------------------------------------------------------------------
// Kernel C: per-edge logits. p = exp(leakyrelu(s_src[src]+s_tgt[tgt]) * w).
// No segment-max subtraction: alpha = p / sum(p) is identical, and |e| is
// O(10) so exp() is safe in f32. Accumulate e_sum[tgt] with HW f32 atomics.
// ---------------------------------------------------------------------------
__global__ __launch_bounds__(256) void gat_edge_logits(
    const int* __restrict__ ei, const float* __restrict__ ew,
    const float* __restrict__ ssrc, const float* __restrict__ stgt,
    float* __restrict__ parr, float* __restrict__ esum, int E)
{
    int e = blockIdx.x * 256 + threadIdx.x;
    if (e >= E) return;
    int s = ei[e];
    int t = ei[E + e];
    float v = ssrc[s] + stgt[t];
    v = (v > 0.f) ? v : NEG_SLOPE * v;
    v *= ew[e];
    float p = __expf(v);
    parr[e] = p;
    unsafeAtomicAdd(&esum[t], p);
}

// ---------------------------------------------------------------------------
// Kernel D: aggregate. 16 threads per edge, float4 per thread (64 channels).
// out[tgt] += (p/(sum+eps)) * Wh[src]  via f32 HW atomics.
// ---------------------------------------------------------------------------
__global__ __launch_bounds__(256) void gat_aggregate(
    const int* __restrict__ ei, const float* __restrict__ parr,
    const float* __restrict__ esum, const float* __restrict__ Wh,
    float* __restrict__ out, int E)
{
    int tid = blockIdx.x * 256 + threadIdx.x;
    int e = tid >> 4;
    int q = tid & 15;
    if (e >= E) return;
    int s = ei[e];
    int t = ei[E + e];
    float alpha = parr[e] / (esum[t] + EPSV);
    float4 wh = *(const float4*)&Wh[(size_t)s * DOUT + q * 4];
    float* op = &out[(size_t)t * DOUT + q * 4];
    unsafeAtomicAdd(op + 0, alpha * wh.x);
    unsafeAtomicAdd(op + 1, alpha * wh.y);
    unsafeAtomicAdd(op + 2, alpha * wh.z);
    unsafeAtomicAdd(op + 3, alpha * wh.w);
}

extern "C" void kernel_launch(void* const* d_in, const int* in_sizes, int n_in,
                              void* d_out, int out_size, void* d_ws, size_t ws_size,
                              hipStream_t stream) {
    const float* x  = (const float*)d_in[0];
    const int*   ei = (const int*)d_in[1];
    const float* ew = (const float*)d_in[2];
    const float* W  = (const float*)d_in[3];
    const float* a  = (const float*)d_in[4];
    const int N = in_sizes[0] / DIN;
    const int E = in_sizes[2];
    float* out = (float*)d_out;

    // Workspace layout (floats): Wh[N*64] | ssrc[N] | stgt[N] | esum[N] | parr[E]
    float* ws   = (float*)d_ws;
    float* Wh   = ws;
    float* ssrc = Wh + (size_t)N * DOUT;
    float* stgt = ssrc + N;
    float* esum = stgt + N;
    float* parr = esum + N;

    hipMemsetAsync(out,  0, (size_t)N * DOUT * sizeof(float), stream);
    hipMemsetAsync(esum, 0, (size_t)N * sizeof(float), stream);

    gat_gemm_scores<<<(N + 63) / 64, 256, 0, stream>>>(x, W, a, Wh, ssrc, stgt, N);
    gat_edge_logits<<<(E + 255) / 256, 256, 0, stream>>>(ei, ew, ssrc, stgt, parr, esum, E);
    gat_aggregate<<<((size_t)E * 16 + 255) / 256, 256, 0, stream>>>(ei, parr, esum, Wh, out, E);
}

// Round 2
// 401.333 us; speedup vs baseline: 3.8883x; 3.8883x over previous
//
#include <hip/hip_runtime.h>
#include <hip/hip_bf16.h>

#define DOUT 64
#define DIN 128
#define NEG_SLOPE 0.2f
#define EPSV 1e-10f
#define LDA 136   // 128 + 8 bf16 pad

typedef __attribute__((ext_vector_type(8))) __bf16 bf16x8;
typedef __attribute__((ext_vector_type(8))) unsigned short ushortx8;
typedef __attribute__((ext_vector_type(4))) float floatx4;

__device__ __forceinline__ unsigned short f32_to_bf16_rne(float f) {
    unsigned int u = __float_as_uint(f);
    u += 0x7fffu + ((u >> 16) & 1u);
    return (unsigned short)(u >> 16);
}

// ---------------------------------------------------------------------------
// Kernel 1: Wh = x @ W via bf16 MFMA; fused s_src = Wh·a[0:64], s_tgt = Wh·a[64:128].
// ---------------------------------------------------------------------------
__global__ __launch_bounds__(256) void gat_gemm_scores(
    const float* __restrict__ x, const float* __restrict__ W,
    const float* __restrict__ a, float* __restrict__ Wh,
    float* __restrict__ ssrc, float* __restrict__ stgt, int N)
{
    __shared__ unsigned short A_sh[64 * LDA];
    __shared__ unsigned short B_sh[64 * LDA];

    const int tid = threadIdx.x;
    const int rowbase = blockIdx.x * 64;

    for (int idx = tid; idx < DIN * DOUT; idx += 256) {
        int k = idx >> 6, n = idx & 63;
        B_sh[n * LDA + k] = f32_to_bf16_rne(W[idx]);
    }
    for (int it = 0; it < 8; ++it) {
        int flat = it * 1024 + tid * 4;
        int row = flat >> 7, k = flat & 127;
        int grow = rowbase + row;
        float4 v = make_float4(0.f, 0.f, 0.f, 0.f);
        if (grow < N) v = *(const float4*)&x[(size_t)grow * DIN + k];
        ushort4 u;
        u.x = f32_to_bf16_rne(v.x); u.y = f32_to_bf16_rne(v.y);
        u.z = f32_to_bf16_rne(v.z); u.w = f32_to_bf16_rne(v.w);
        *(ushort4*)&A_sh[row * LDA + k] = u;
    }
    __syncthreads();

    const int lane = tid & 63;
    const int wv   = tid >> 6;
    const int c16  = lane & 15;
    const int quad = lane >> 4;

    floatx4 acc[4] = {floatx4{0,0,0,0}, floatx4{0,0,0,0},
                      floatx4{0,0,0,0}, floatx4{0,0,0,0}};

    const int arow = (wv * 16 + c16) * LDA;
    #pragma unroll
    for (int kk = 0; kk < 4; ++kk) {
        const int koff = kk * 32 + quad * 8;
        bf16x8 af = __builtin_bit_cast(bf16x8, *(const ushortx8*)&A_sh[arow + koff]);
        #pragma unroll
        for (int nt = 0; nt < 4; ++nt) {
            bf16x8 bf = __builtin_bit_cast(bf16x8,
                           *(const ushortx8*)&B_sh[(nt * 16 + c16) * LDA + koff]);
            acc[nt] = __builtin_amdgcn_mfma_f32_16x16x32_bf16(af, bf, acc[nt], 0, 0, 0);
        }
    }

    float asrc_v[4], atgt_v[4];
    #pragma unroll
    for (int nt = 0; nt < 4; ++nt) {
        asrc_v[nt] = a[nt * 16 + c16];
        atgt_v[nt] = a[64 + nt * 16 + c16];
    }
    const int rbase = rowbase + wv * 16 + quad * 4;
    #pragma unroll
    for (int r = 0; r < 4; ++r) {
        int row = rbase + r;
        if (row < N) {
            #pragma unroll
            for (int nt = 0; nt < 4; ++nt)
                Wh[(size_t)row * DOUT + nt * 16 + c16] = acc[nt][r];
        }
    }
    #pragma unroll
    for (int r = 0; r < 4; ++r) {
        float ps = 0.f, pt = 0.f;
        #pragma unroll
        for (int nt = 0; nt < 4; ++nt) {
            ps += acc[nt][r] * asrc_v[nt];
            pt += acc[nt][r] * atgt_v[nt];
        }
        #pragma unroll
        for (int m = 1; m < 16; m <<= 1) {
            ps += __shfl_xor(ps, m);
            pt += __shfl_xor(pt, m);
        }
        if (c16 == 0) {
            int row = rbase + r;
            if (row < N) { ssrc[row] = ps; stgt[row] = pt; }
        }
    }
}

// ---------------------------------------------------------------------------
// Kernel 2: histogram of targets. cnt[t]++ per edge.
// ---------------------------------------------------------------------------
__global__ __launch_bounds__(256) void gat_hist(
    const int* __restrict__ ei, int* __restrict__ cnt, int E)
{
    int e = blockIdx.x * 256 + threadIdx.x;
    if (e >= E) return;
    atomicAdd(&cnt[ei[E + e]], 1);
}

// ---------------------------------------------------------------------------
// Kernels 3-5: exclusive scan of cnt[N] -> row_ptr[N+1] (+ cur copy).
// Chunk = 1024 per block (256 thr x 4).
// ---------------------------------------------------------------------------
__global__ __launch_bounds__(256) void gat_scan_part(
    const int* __restrict__ cnt, int* __restrict__ bsum, int N)
{
    __shared__ int lds[256];
    int base = blockIdx.x * 1024 + threadIdx.x * 4;
    int s = 0;
    #pragma unroll
    for (int j = 0; j < 4; ++j) { int g = base + j; s += (g < N) ? cnt[g] : 0; }
    lds[threadIdx.x] = s; __syncthreads();
    for (int off = 128; off > 0; off >>= 1) {
        if (threadIdx.x < off) lds[threadIdx.x] += lds[threadIdx.x + off];
        __syncthreads();
    }
    if (threadIdx.x == 0) bsum[blockIdx.x] = lds[0];
}

__global__ __launch_bounds__(256) void gat_scan_mid(
    const int* __restrict__ bsum, int* __restrict__ bscan, int nb)
{
    __shared__ int lds[256];
    int i = threadIdx.x;
    if (i < nb) lds[i] = bsum[i];
    __syncthreads();
    if (i == 0) {
        int acc = 0;
        for (int j = 0; j < nb; ++j) { int c = lds[j]; lds[j] = acc; acc += c; }
    }
    __syncthreads();
    if (i < nb) bscan[i] = lds[i];
}

__global__ __launch_bounds__(256) void gat_scan_add(
    const int* __restrict__ cnt, const int* __restrict__ bscan,
    int* __restrict__ row_ptr, int* __restrict__ cur, int N, int E)
{
    __shared__ int lds[256];
    int base = blockIdx.x * 1024 + threadIdx.x * 4;
    int c[4]; int s = 0;
    #pragma unroll
    for (int j = 0; j < 4; ++j) { int g = base + j; c[j] = (g < N) ? cnt[g] : 0; s += c[j]; }
    lds[threadIdx.x] = s; __syncthreads();
    for (int off = 1; off < 256; off <<= 1) {
        int t = 0;
        if (threadIdx.x >= off) t = lds[threadIdx.x - off];
        __syncthreads();
        lds[threadIdx.x] += t;
        __syncthreads();
    }
    int run = bscan[blockIdx.x] + lds[threadIdx.x] - s;  // exclusive prefix
    #pragma unroll
    for (int j = 0; j < 4; ++j) {
        int g = base + j;
        if (g < N) { row_ptr[g] = run; cur[g] = run; }
        run += c[j];
    }
    if (blockIdx.x == 0 && threadIdx.x == 0) row_ptr[N] = E;
}

// ---------------------------------------------------------------------------
// Kernel 6: scatter edges into CSR order; compute p = exp(leakyrelu(.)·w) inline.
// ---------------------------------------------------------------------------
__global__ __launch_bounds__(256) void gat_scatter(
    const int* __restrict__ ei, const float* __restrict__ ew,
    const float* __restrict__ ssrc, const float* __restrict__ stgt,
    int* __restrict__ cur, int* __restrict__ sorted_src,
    float* __restrict__ sorted_p, int E)
{
    int e = blockIdx.x * 256 + threadIdx.x;
    if (e >= E) return;
    int s = ei[e];
    int t = ei[E + e];
    float v = ssrc[s] + stgt[t];
    v = (v > 0.f) ? v : NEG_SLOPE * v;
    v *= ew[e];
    float p = __expf(v);
    int pos = atomicAdd(&cur[t], 1);
    sorted_src[pos] = s;
    sorted_p[pos]   = p;
}

// ---------------------------------------------------------------------------
// Kernel 7: segmented reduction. One wave per target node, lane = channel.
// out[t] = (Σ p·Wh[src]) / (Σ p + eps). No atomics; each out row written once.
// ---------------------------------------------------------------------------
__global__ __launch_bounds__(256) void gat_aggregate_csr(
    const int* __restrict__ row_ptr, const int* __restrict__ sorted_src,
    const float* __restrict__ sorted_p, const float* __restrict__ Wh,
    float* __restrict__ out, int N)
{
    int t = blockIdx.x * 4 + (threadIdx.x >> 6);
    if (t >= N) return;
    int lane = threadIdx.x & 63;
    int beg = row_ptr[t], end = row_ptr[t + 1];

    float acc0 = 0.f, acc1 = 0.f, ps0 = 0.f, ps1 = 0.f;
    int i = beg;
    for (; i + 1 < end; i += 2) {
        int s0 = sorted_src[i], s1 = sorted_src[i + 1];
        float p0 = sorted_p[i], p1 = sorted_p[i + 1];
        acc0 += p0 * Wh[(size_t)s0 * DOUT + lane];
        acc1 += p1 * Wh[(size_t)s1 * DOUT + lane];
        ps0 += p0; ps1 += p1;
    }
    if (i < end) {
        int s = sorted_src[i];
        float p = sorted_p[i];
        acc0 += p * Wh[(size_t)s * DOUT + lane];
        ps0 += p;
    }
    float inv = 1.0f / ((ps0 + ps1) + EPSV);
    out[(size_t)t * DOUT + lane] = (acc0 + acc1) * inv;
}

extern "C" void kernel_launch(void* const* d_in, const int* in_sizes, int n_in,
                              void* d_out, int out_size, void* d_ws, size_t ws_size,
                              hipStream_t stream) {
    const float* x  = (const float*)d_in[0];
    const int*   ei = (const int*)d_in[1];
    const float* ew = (const float*)d_in[2];
    const float* W  = (const float*)d_in[3];
    const float* a  = (const float*)d_in[4];
    const int N = in_sizes[0] / DIN;
    const int E = in_sizes[2];
    float* out = (float*)d_out;

    // Workspace layout (4B elems):
    // Wh[N*64] | ssrc[N] | stgt[N] | cnt[N] | row_ptr[N+1] | cur[N] |
    // bsum[256] | bscan[256] | sorted_src[E] | sorted_p[E]
    char* wsb = (char*)d_ws;
    float* Wh        = (float*)wsb;                 wsb += (size_t)N * DOUT * 4;
    float* ssrc      = (float*)wsb;                 wsb += (size_t)N * 4;
    float* stgt      = (float*)wsb;                 wsb += (size_t)N * 4;
    int*   cnt       = (int*)wsb;                   wsb += (size_t)N * 4;
    int*   row_ptr   = (int*)wsb;                   wsb += (size_t)(N + 1) * 4;
    int*   cur       = (int*)wsb;                   wsb += (size_t)N * 4;
    int*   bsum      = (int*)wsb;                   wsb += 256 * 4;
    int*   bscan     = (int*)wsb;                   wsb += 256 * 4;
    int*   sorted_src= (int*)wsb;                   wsb += (size_t)E * 4;
    float* sorted_p  = (float*)wsb;                 wsb += (size_t)E * 4;

    const int nb = (N + 1023) / 1024;

    hipMemsetAsync(cnt, 0, (size_t)N * sizeof(int), stream);

    gat_gemm_scores<<<(N + 63) / 64, 256, 0, stream>>>(x, W, a, Wh, ssrc, stgt, N);
    gat_hist      <<<(E + 255) / 256, 256, 0, stream>>>(ei, cnt, E);
    gat_scan_part <<<nb, 256, 0, stream>>>(cnt, bsum, N);
    gat_scan_mid  <<<1, 256, 0, stream>>>(bsum, bscan, nb);
    gat_scan_add  <<<nb, 256, 0, stream>>>(cnt, bscan, row_ptr, cur, N, E);
    gat_scatter   <<<(E + 255) / 256, 256, 0, stream>>>(ei, ew, ssrc, stgt, cur,
                                                        sorted_src, sorted_p, E);
    gat_aggregate_csr<<<(N + 3) / 4, 256, 0, stream>>>(row_ptr, sorted_src, sorted_p,
                                                       Wh, out, N);
}

// Round 3
// 370.202 us; speedup vs baseline: 4.2152x; 1.0841x over previous
//
#include <hip/hip_runtime.h>
#include <hip/hip_bf16.h>

#define DOUT 64
#define DIN 128
#define NEG_SLOPE 0.2f
#define EPSV 1e-10f
#define LDA 136   // 128 + 8 bf16 pad

typedef __attribute__((ext_vector_type(8))) __bf16 bf16x8;
typedef __attribute__((ext_vector_type(8))) unsigned short ushortx8;
typedef __attribute__((ext_vector_type(4))) float floatx4;

__device__ __forceinline__ unsigned short f32_to_bf16_rne(float f) {
    unsigned int u = __float_as_uint(f);
    u += 0x7fffu + ((u >> 16) & 1u);
    return (unsigned short)(u >> 16);
}
__device__ __forceinline__ float bf16_to_f32(unsigned short u) {
    return __uint_as_float(((unsigned int)u) << 16);
}

// ---------------------------------------------------------------------------
// Kernel 1: Wh = x @ W via bf16 MFMA; fused s_src = Wh·a[0:64], s_tgt = Wh·a[64:128].
// Wh stored as bf16 (halves write + downstream gather traffic).
// ---------------------------------------------------------------------------
__global__ __launch_bounds__(256) void gat_gemm_scores(
    const float* __restrict__ x, const float* __restrict__ W,
    const float* __restrict__ a, unsigned short* __restrict__ Wh,
    float* __restrict__ ssrc, float* __restrict__ stgt, int N)
{
    __shared__ unsigned short A_sh[64 * LDA];
    __shared__ unsigned short B_sh[64 * LDA];

    const int tid = threadIdx.x;
    const int rowbase = blockIdx.x * 64;

    for (int idx = tid; idx < DIN * DOUT; idx += 256) {
        int k = idx >> 6, n = idx & 63;
        B_sh[n * LDA + k] = f32_to_bf16_rne(W[idx]);
    }
    for (int it = 0; it < 8; ++it) {
        int flat = it * 1024 + tid * 4;
        int row = flat >> 7, k = flat & 127;
        int grow = rowbase + row;
        float4 v = make_float4(0.f, 0.f, 0.f, 0.f);
        if (grow < N) v = *(const float4*)&x[(size_t)grow * DIN + k];
        ushort4 u;
        u.x = f32_to_bf16_rne(v.x); u.y = f32_to_bf16_rne(v.y);
        u.z = f32_to_bf16_rne(v.z); u.w = f32_to_bf16_rne(v.w);
        *(ushort4*)&A_sh[row * LDA + k] = u;
    }
    __syncthreads();

    const int lane = tid & 63;
    const int wv   = tid >> 6;
    const int c16  = lane & 15;
    const int quad = lane >> 4;

    floatx4 acc[4] = {floatx4{0,0,0,0}, floatx4{0,0,0,0},
                      floatx4{0,0,0,0}, floatx4{0,0,0,0}};

    const int arow = (wv * 16 + c16) * LDA;
    #pragma unroll
    for (int kk = 0; kk < 4; ++kk) {
        const int koff = kk * 32 + quad * 8;
        bf16x8 af = __builtin_bit_cast(bf16x8, *(const ushortx8*)&A_sh[arow + koff]);
        #pragma unroll
        for (int nt = 0; nt < 4; ++nt) {
            bf16x8 bf = __builtin_bit_cast(bf16x8,
                           *(const ushortx8*)&B_sh[(nt * 16 + c16) * LDA + koff]);
            acc[nt] = __builtin_amdgcn_mfma_f32_16x16x32_bf16(af, bf, acc[nt], 0, 0, 0);
        }
    }

    float asrc_v[4], atgt_v[4];
    #pragma unroll
    for (int nt = 0; nt < 4; ++nt) {
        asrc_v[nt] = a[nt * 16 + c16];
        atgt_v[nt] = a[64 + nt * 16 + c16];
    }
    const int rbase = rowbase + wv * 16 + quad * 4;
    #pragma unroll
    for (int r = 0; r < 4; ++r) {
        int row = rbase + r;
        if (row < N) {
            #pragma unroll
            for (int nt = 0; nt < 4; ++nt)
                Wh[(size_t)row * DOUT + nt * 16 + c16] = f32_to_bf16_rne(acc[nt][r]);
        }
    }
    #pragma unroll
    for (int r = 0; r < 4; ++r) {
        float ps = 0.f, pt = 0.f;
        #pragma unroll
        for (int nt = 0; nt < 4; ++nt) {
            ps += acc[nt][r] * asrc_v[nt];
            pt += acc[nt][r] * atgt_v[nt];
        }
        #pragma unroll
        for (int m = 1; m < 16; m <<= 1) {
            ps += __shfl_xor(ps, m);
            pt += __shfl_xor(pt, m);
        }
        if (c16 == 0) {
            int row = rbase + r;
            if (row < N) { ssrc[row] = ps; stgt[row] = pt; }
        }
    }
}

// ---------------------------------------------------------------------------
// Kernel 2: histogram of targets, 4 edges per thread.
// ---------------------------------------------------------------------------
__global__ __launch_bounds__(256) void gat_hist(
    const int* __restrict__ ei, int* __restrict__ cnt, int E)
{
    int e4 = (blockIdx.x * 256 + threadIdx.x) * 4;
    if (e4 + 3 < E) {
        int4 t = *(const int4*)&ei[E + e4];
        atomicAdd(&cnt[t.x], 1);
        atomicAdd(&cnt[t.y], 1);
        atomicAdd(&cnt[t.z], 1);
        atomicAdd(&cnt[t.w], 1);
    } else {
        for (int e = e4; e < E; ++e) atomicAdd(&cnt[ei[E + e]], 1);
    }
}

// ---------------------------------------------------------------------------
// Kernels 3-5: exclusive scan of cnt[N] -> row_ptr[N+1] (+ cur copy).
// ---------------------------------------------------------------------------
__global__ __launch_bounds__(256) void gat_scan_part(
    const int* __restrict__ cnt, int* __restrict__ bsum, int N)
{
    __shared__ int lds[256];
    int base = blockIdx.x * 1024 + threadIdx.x * 4;
    int s = 0;
    #pragma unroll
    for (int j = 0; j < 4; ++j) { int g = base + j; s += (g < N) ? cnt[g] : 0; }
    lds[threadIdx.x] = s; __syncthreads();
    for (int off = 128; off > 0; off >>= 1) {
        if (threadIdx.x < off) lds[threadIdx.x] += lds[threadIdx.x + off];
        __syncthreads();
    }
    if (threadIdx.x == 0) bsum[blockIdx.x] = lds[0];
}

__global__ __launch_bounds__(256) void gat_scan_mid(
    const int* __restrict__ bsum, int* __restrict__ bscan, int nb)
{
    __shared__ int lds[256];
    int i = threadIdx.x;
    if (i < nb) lds[i] = bsum[i];
    __syncthreads();
    if (i == 0) {
        int acc = 0;
        for (int j = 0; j < nb; ++j) { int c = lds[j]; lds[j] = acc; acc += c; }
    }
    __syncthreads();
    if (i < nb) bscan[i] = lds[i];
}

__global__ __launch_bounds__(256) void gat_scan_add(
    const int* __restrict__ cnt, const int* __restrict__ bscan,
    int* __restrict__ row_ptr, int* __restrict__ cur, int N, int E)
{
    __shared__ int lds[256];
    int base = blockIdx.x * 1024 + threadIdx.x * 4;
    int c[4]; int s = 0;
    #pragma unroll
    for (int j = 0; j < 4; ++j) { int g = base + j; c[j] = (g < N) ? cnt[g] : 0; s += c[j]; }
    lds[threadIdx.x] = s; __syncthreads();
    for (int off = 1; off < 256; off <<= 1) {
        int t = 0;
        if (threadIdx.x >= off) t = lds[threadIdx.x - off];
        __syncthreads();
        lds[threadIdx.x] += t;
        __syncthreads();
    }
    int run = bscan[blockIdx.x] + lds[threadIdx.x] - s;  // exclusive prefix
    #pragma unroll
    for (int j = 0; j < 4; ++j) {
        int g = base + j;
        if (g < N) { row_ptr[g] = run; cur[g] = run; }
        run += c[j];
    }
    if (blockIdx.x == 0 && threadIdx.x == 0) row_ptr[N] = E;
}

// ---------------------------------------------------------------------------
// Kernel 6: scatter edges into CSR order as packed int2{src, p_bits}.
// One 8B store per edge (halves dirtied sectors vs two 4B arrays).
// ---------------------------------------------------------------------------
__global__ __launch_bounds__(256) void gat_scatter(
    const int* __restrict__ ei, const float* __restrict__ ew,
    const float* __restrict__ ssrc, const float* __restrict__ stgt,
    int* __restrict__ cur, int2* __restrict__ sorted_sp, int E)
{
    int e = blockIdx.x * 256 + threadIdx.x;
    if (e >= E) return;
    int s = ei[e];
    int t = ei[E + e];
    float v = ssrc[s] + stgt[t];
    v = (v > 0.f) ? v : NEG_SLOPE * v;
    v *= ew[e];
    float p = __expf(v);
    int pos = atomicAdd(&cur[t], 1);
    sorted_sp[pos] = make_int2(s, __float_as_int(p));
}

// ---------------------------------------------------------------------------
// Kernel 7: segmented reduction. One wave per target node, lane = channel.
// out[t] = (Σ p·Wh[src]) / (Σ p + eps). Wh gathered as bf16.
// ---------------------------------------------------------------------------
__global__ __launch_bounds__(256) void gat_aggregate_csr(
    const int* __restrict__ row_ptr, const int2* __restrict__ sorted_sp,
    const unsigned short* __restrict__ Wh, float* __restrict__ out, int N)
{
    int t = blockIdx.x * 4 + (threadIdx.x >> 6);
    if (t >= N) return;
    int lane = threadIdx.x & 63;
    int beg = row_ptr[t], end = row_ptr[t + 1];

    float acc0 = 0.f, acc1 = 0.f, ps0 = 0.f, ps1 = 0.f;
    int i = beg;
    for (; i + 1 < end; i += 2) {
        int2 sp0 = sorted_sp[i];
        int2 sp1 = sorted_sp[i + 1];
        float p0 = __int_as_float(sp0.y);
        float p1 = __int_as_float(sp1.y);
        unsigned short w0 = Wh[(size_t)sp0.x * DOUT + lane];
        unsigned short w1 = Wh[(size_t)sp1.x * DOUT + lane];
        acc0 += p0 * bf16_to_f32(w0);
        acc1 += p1 * bf16_to_f32(w1);
        ps0 += p0; ps1 += p1;
    }
    if (i < end) {
        int2 sp = sorted_sp[i];
        float p = __int_as_float(sp.y);
        acc0 += p * bf16_to_f32(Wh[(size_t)sp.x * DOUT + lane]);
        ps0 += p;
    }
    float inv = 1.0f / ((ps0 + ps1) + EPSV);
    out[(size_t)t * DOUT + lane] = (acc0 + acc1) * inv;
}

extern "C" void kernel_launch(void* const* d_in, const int* in_sizes, int n_in,
                              void* d_out, int out_size, void* d_ws, size_t ws_size,
                              hipStream_t stream) {
    const float* x  = (const float*)d_in[0];
    const int*   ei = (const int*)d_in[1];
    const float* ew = (const float*)d_in[2];
    const float* W  = (const float*)d_in[3];
    const float* a  = (const float*)d_in[4];
    const int N = in_sizes[0] / DIN;
    const int E = in_sizes[2];
    float* out = (float*)d_out;

    // Workspace layout:
    // Wh[N*64] bf16 | ssrc[N] f32 | stgt[N] f32 | cnt[N] | row_ptr[N+1] | cur[N]
    // | bsum[256] | bscan[256] | sorted_sp[E] int2
    char* wsb = (char*)d_ws;
    unsigned short* Wh = (unsigned short*)wsb;      wsb += (size_t)N * DOUT * 2;
    float* ssrc      = (float*)wsb;                 wsb += (size_t)N * 4;
    float* stgt      = (float*)wsb;                 wsb += (size_t)N * 4;
    int*   cnt       = (int*)wsb;                   wsb += (size_t)N * 4;
    int*   row_ptr   = (int*)wsb;                   wsb += (size_t)(N + 1) * 4;
    int*   cur       = (int*)wsb;                   wsb += (size_t)N * 4;
    int*   bsum      = (int*)wsb;                   wsb += 256 * 4;
    int*   bscan     = (int*)wsb;                   wsb += 256 * 4;
    wsb = (char*)(((uintptr_t)wsb + 15) & ~(uintptr_t)15);
    int2*  sorted_sp = (int2*)wsb;                  wsb += (size_t)E * 8;

    const int nb = (N + 1023) / 1024;

    hipMemsetAsync(cnt, 0, (size_t)N * sizeof(int), stream);

    gat_gemm_scores<<<(N + 63) / 64, 256, 0, stream>>>(x, W, a, Wh, ssrc, stgt, N);
    gat_hist      <<<(E / 4 + 255) / 256, 256, 0, stream>>>(ei, cnt, E);
    gat_scan_part <<<nb, 256, 0, stream>>>(cnt, bsum, N);
    gat_scan_mid  <<<1, 256, 0, stream>>>(bsum, bscan, nb);
    gat_scan_add  <<<nb, 256, 0, stream>>>(cnt, bscan, row_ptr, cur, N, E);
    gat_scatter   <<<(E + 255) / 256, 256, 0, stream>>>(ei, ew, ssrc, stgt, cur,
                                                        sorted_sp, E);
    gat_aggregate_csr<<<(N + 3) / 4, 256, 0, stream>>>(row_ptr, sorted_sp, Wh, out, N);
}

// Round 4
// 320.967 us; speedup vs baseline: 4.8618x; 1.1534x over previous
//
#include <hip/hip_runtime.h>
#include <hip/hip_bf16.h>

#define DOUT 64
#define DIN 128
#define NEG_SLOPE 0.2f
#define EPSV 1e-10f
#define LDA 136   // 128 + 8 bf16 pad

typedef __attribute__((ext_vector_type(8))) __bf16 bf16x8;
typedef __attribute__((ext_vector_type(8))) unsigned short ushortx8;
typedef __attribute__((ext_vector_type(4))) float floatx4;

__device__ __forceinline__ unsigned short f32_to_bf16_rne(float f) {
    unsigned int u = __float_as_uint(f);
    u += 0x7fffu + ((u >> 16) & 1u);
    return (unsigned short)(u >> 16);
}
__device__ __forceinline__ float bf16_to_f32(unsigned short u) {
    return __uint_as_float(((unsigned int)u) << 16);
}

// ---------------------------------------------------------------------------
// Kernel 1: Wh = x @ W via bf16 MFMA; fused s_src = Wh·a[0:64], s_tgt = Wh·a[64:128].
// Wh stored as bf16.
// ---------------------------------------------------------------------------
__global__ __launch_bounds__(256) void gat_gemm_scores(
    const float* __restrict__ x, const float* __restrict__ W,
    const float* __restrict__ a, unsigned short* __restrict__ Wh,
    float* __restrict__ ssrc, float* __restrict__ stgt, int N)
{
    __shared__ unsigned short A_sh[64 * LDA];
    __shared__ unsigned short B_sh[64 * LDA];

    const int tid = threadIdx.x;
    const int rowbase = blockIdx.x * 64;

    for (int idx = tid; idx < DIN * DOUT; idx += 256) {
        int k = idx >> 6, n = idx & 63;
        B_sh[n * LDA + k] = f32_to_bf16_rne(W[idx]);
    }
    for (int it = 0; it < 8; ++it) {
        int flat = it * 1024 + tid * 4;
        int row = flat >> 7, k = flat & 127;
        int grow = rowbase + row;
        float4 v = make_float4(0.f, 0.f, 0.f, 0.f);
        if (grow < N) v = *(const float4*)&x[(size_t)grow * DIN + k];
        ushort4 u;
        u.x = f32_to_bf16_rne(v.x); u.y = f32_to_bf16_rne(v.y);
        u.z = f32_to_bf16_rne(v.z); u.w = f32_to_bf16_rne(v.w);
        *(ushort4*)&A_sh[row * LDA + k] = u;
    }
    __syncthreads();

    const int lane = tid & 63;
    const int wv   = tid >> 6;
    const int c16  = lane & 15;
    const int quad = lane >> 4;

    floatx4 acc[4] = {floatx4{0,0,0,0}, floatx4{0,0,0,0},
                      floatx4{0,0,0,0}, floatx4{0,0,0,0}};

    const int arow = (wv * 16 + c16) * LDA;
    #pragma unroll
    for (int kk = 0; kk < 4; ++kk) {
        const int koff = kk * 32 + quad * 8;
        bf16x8 af = __builtin_bit_cast(bf16x8, *(const ushortx8*)&A_sh[arow + koff]);
        #pragma unroll
        for (int nt = 0; nt < 4; ++nt) {
            bf16x8 bf = __builtin_bit_cast(bf16x8,
                           *(const ushortx8*)&B_sh[(nt * 16 + c16) * LDA + koff]);
            acc[nt] = __builtin_amdgcn_mfma_f32_16x16x32_bf16(af, bf, acc[nt], 0, 0, 0);
        }
    }

    float asrc_v[4], atgt_v[4];
    #pragma unroll
    for (int nt = 0; nt < 4; ++nt) {
        asrc_v[nt] = a[nt * 16 + c16];
        atgt_v[nt] = a[64 + nt * 16 + c16];
    }
    const int rbase = rowbase + wv * 16 + quad * 4;
    #pragma unroll
    for (int r = 0; r < 4; ++r) {
        int row = rbase + r;
        if (row < N) {
            #pragma unroll
            for (int nt = 0; nt < 4; ++nt)
                Wh[(size_t)row * DOUT + nt * 16 + c16] = f32_to_bf16_rne(acc[nt][r]);
        }
    }
    #pragma unroll
    for (int r = 0; r < 4; ++r) {
        float ps = 0.f, pt = 0.f;
        #pragma unroll
        for (int nt = 0; nt < 4; ++nt) {
            ps += acc[nt][r] * asrc_v[nt];
            pt += acc[nt][r] * atgt_v[nt];
        }
        #pragma unroll
        for (int m = 1; m < 16; m <<= 1) {
            ps += __shfl_xor(ps, m);
            pt += __shfl_xor(pt, m);
        }
        if (c16 == 0) {
            int row = rbase + r;
            if (row < N) { ssrc[row] = ps; stgt[row] = pt; }
        }
    }
}

// ---------------------------------------------------------------------------
// Kernel 2: histogram of targets, 4 edges per thread.
// ---------------------------------------------------------------------------
__global__ __launch_bounds__(256) void gat_hist(
    const int* __restrict__ ei, int* __restrict__ cnt, int E)
{
    int e4 = (blockIdx.x * 256 + threadIdx.x) * 4;
    if (e4 + 3 < E) {
        int4 t = *(const int4*)&ei[E + e4];
        atomicAdd(&cnt[t.x], 1);
        atomicAdd(&cnt[t.y], 1);
        atomicAdd(&cnt[t.z], 1);
        atomicAdd(&cnt[t.w], 1);
    } else {
        for (int e = e4; e < E; ++e) atomicAdd(&cnt[ei[E + e]], 1);
    }
}

// ---------------------------------------------------------------------------
// Kernels 3-5: exclusive scan of cnt[N] -> row_ptr[N+1] (+ cur copy).
// ---------------------------------------------------------------------------
__global__ __launch_bounds__(256) void gat_scan_part(
    const int* __restrict__ cnt, int* __restrict__ bsum, int N)
{
    __shared__ int lds[256];
    int base = blockIdx.x * 1024 + threadIdx.x * 4;
    int s = 0;
    #pragma unroll
    for (int j = 0; j < 4; ++j) { int g = base + j; s += (g < N) ? cnt[g] : 0; }
    lds[threadIdx.x] = s; __syncthreads();
    for (int off = 128; off > 0; off >>= 1) {
        if (threadIdx.x < off) lds[threadIdx.x] += lds[threadIdx.x + off];
        __syncthreads();
    }
    if (threadIdx.x == 0) bsum[blockIdx.x] = lds[0];
}

__global__ __launch_bounds__(256) void gat_scan_mid(
    const int* __restrict__ bsum, int* __restrict__ bscan, int nb)
{
    __shared__ int lds[256];
    int i = threadIdx.x;
    if (i < nb) lds[i] = bsum[i];
    __syncthreads();
    if (i == 0) {
        int acc = 0;
        for (int j = 0; j < nb; ++j) { int c = lds[j]; lds[j] = acc; acc += c; }
    }
    __syncthreads();
    if (i < nb) bscan[i] = lds[i];
}

__global__ __launch_bounds__(256) void gat_scan_add(
    const int* __restrict__ cnt, const int* __restrict__ bscan,
    int* __restrict__ row_ptr, int* __restrict__ cur, int N, int E)
{
    __shared__ int lds[256];
    int base = blockIdx.x * 1024 + threadIdx.x * 4;
    int c[4]; int s = 0;
    #pragma unroll
    for (int j = 0; j < 4; ++j) { int g = base + j; c[j] = (g < N) ? cnt[g] : 0; s += c[j]; }
    lds[threadIdx.x] = s; __syncthreads();
    for (int off = 1; off < 256; off <<= 1) {
        int t = 0;
        if (threadIdx.x >= off) t = lds[threadIdx.x - off];
        __syncthreads();
        lds[threadIdx.x] += t;
        __syncthreads();
    }
    int run = bscan[blockIdx.x] + lds[threadIdx.x] - s;  // exclusive prefix
    #pragma unroll
    for (int j = 0; j < 4; ++j) {
        int g = base + j;
        if (g < N) { row_ptr[g] = run; cur[g] = run; }
        run += c[j];
    }
    if (blockIdx.x == 0 && threadIdx.x == 0) row_ptr[N] = E;
}

// ---------------------------------------------------------------------------
// Kernel 6: scatter edges into CSR order as packed int2{src, p_bits}.
// ---------------------------------------------------------------------------
__global__ __launch_bounds__(256) void gat_scatter(
    const int* __restrict__ ei, const float* __restrict__ ew,
    const float* __restrict__ ssrc, const float* __restrict__ stgt,
    int* __restrict__ cur, int2* __restrict__ sorted_sp, int E)
{
    int e = blockIdx.x * 256 + threadIdx.x;
    if (e >= E) return;
    int s = ei[e];
    int t = ei[E + e];
    float v = ssrc[s] + stgt[t];
    v = (v > 0.f) ? v : NEG_SLOPE * v;
    v *= ew[e];
    float p = __expf(v);
    int pos = atomicAdd(&cur[t], 1);
    sorted_sp[pos] = make_int2(s, __float_as_int(p));
}

// ---------------------------------------------------------------------------
// Kernel 7: segmented reduction. One wave per target node; wave split into
// 4 x 16-lane groups, each group owns one edge per iteration; each lane holds
// 4 channels (ushort4 = 8B load; 16 lanes cover the 128B bf16 row).
// Cross-group combine via shfl_xor(16),shfl_xor(32) at the end.
// ---------------------------------------------------------------------------
__global__ __launch_bounds__(256) void gat_aggregate_csr(
    const int* __restrict__ row_ptr, const int2* __restrict__ sorted_sp,
    const unsigned short* __restrict__ Wh, float* __restrict__ out, int N)
{
    int t = blockIdx.x * 4 + (threadIdx.x >> 6);
    if (t >= N) return;
    int lane = threadIdx.x & 63;
    int sub  = lane >> 4;    // edge slot 0..3
    int c16  = lane & 15;    // channel group: channels c16*4 .. c16*4+3

    int beg = row_ptr[t], end = row_ptr[t + 1];

    float a0 = 0.f, a1 = 0.f, a2 = 0.f, a3 = 0.f, psum = 0.f;

    int i = beg + sub;
    // 2-way unroll: two independent gather chains in flight per group.
    for (; i + 4 < end; i += 8) {
        int2 spA = sorted_sp[i];
        int2 spB = sorted_sp[i + 4];
        float pA = __int_as_float(spA.y);
        float pB = __int_as_float(spB.y);
        ushort4 wA = *(const ushort4*)&Wh[(size_t)spA.x * DOUT + c16 * 4];
        ushort4 wB = *(const ushort4*)&Wh[(size_t)spB.x * DOUT + c16 * 4];
        a0 += pA * bf16_to_f32(wA.x); a1 += pA * bf16_to_f32(wA.y);
        a2 += pA * bf16_to_f32(wA.z); a3 += pA * bf16_to_f32(wA.w);
        psum += pA;
        a0 += pB * bf16_to_f32(wB.x); a1 += pB * bf16_to_f32(wB.y);
        a2 += pB * bf16_to_f32(wB.z); a3 += pB * bf16_to_f32(wB.w);
        psum += pB;
    }
    if (i < end) {
        int2 sp = sorted_sp[i];
        float p = __int_as_float(sp.y);
        ushort4 w = *(const ushort4*)&Wh[(size_t)sp.x * DOUT + c16 * 4];
        a0 += p * bf16_to_f32(w.x); a1 += p * bf16_to_f32(w.y);
        a2 += p * bf16_to_f32(w.z); a3 += p * bf16_to_f32(w.w);
        psum += p;
    }

    // combine the 4 edge-groups (lanes with equal c16 across subs)
    #pragma unroll
    for (int m = 16; m < 64; m <<= 1) {
        a0 += __shfl_xor(a0, m);
        a1 += __shfl_xor(a1, m);
        a2 += __shfl_xor(a2, m);
        a3 += __shfl_xor(a3, m);
        psum += __shfl_xor(psum, m);
    }

    if (sub == 0) {
        float inv = 1.0f / (psum + EPSV);
        float4 o = make_float4(a0 * inv, a1 * inv, a2 * inv, a3 * inv);
        *(float4*)&out[(size_t)t * DOUT + c16 * 4] = o;
    }
}

extern "C" void kernel_launch(void* const* d_in, const int* in_sizes, int n_in,
                              void* d_out, int out_size, void* d_ws, size_t ws_size,
                              hipStream_t stream) {
    const float* x  = (const float*)d_in[0];
    const int*   ei = (const int*)d_in[1];
    const float* ew = (const float*)d_in[2];
    const float* W  = (const float*)d_in[3];
    const float* a  = (const float*)d_in[4];
    const int N = in_sizes[0] / DIN;
    const int E = in_sizes[2];
    float* out = (float*)d_out;

    char* wsb = (char*)d_ws;
    unsigned short* Wh = (unsigned short*)wsb;      wsb += (size_t)N * DOUT * 2;
    float* ssrc      = (float*)wsb;                 wsb += (size_t)N * 4;
    float* stgt      = (float*)wsb;                 wsb += (size_t)N * 4;
    int*   cnt       = (int*)wsb;                   wsb += (size_t)N * 4;
    int*   row_ptr   = (int*)wsb;                   wsb += (size_t)(N + 1) * 4;
    int*   cur       = (int*)wsb;                   wsb += (size_t)N * 4;
    int*   bsum      = (int*)wsb;                   wsb += 256 * 4;
    int*   bscan     = (int*)wsb;                   wsb += 256 * 4;
    wsb = (char*)(((uintptr_t)wsb + 15) & ~(uintptr_t)15);
    int2*  sorted_sp = (int2*)wsb;                  wsb += (size_t)E * 8;

    const int nb = (N + 1023) / 1024;

    hipMemsetAsync(cnt, 0, (size_t)N * sizeof(int), stream);

    gat_gemm_scores<<<(N + 63) / 64, 256, 0, stream>>>(x, W, a, Wh, ssrc, stgt, N);
    gat_hist      <<<(E / 4 + 255) / 256, 256, 0, stream>>>(ei, cnt, E);
    gat_scan_part <<<nb, 256, 0, stream>>>(cnt, bsum, N);
    gat_scan_mid  <<<1, 256, 0, stream>>>(bsum, bscan, nb);
    gat_scan_add  <<<nb, 256, 0, stream>>>(cnt, bscan, row_ptr, cur, N, E);
    gat_scatter   <<<(E + 255) / 256, 256, 0, stream>>>(ei, ew, ssrc, stgt, cur,
                                                        sorted_sp, E);
    gat_aggregate_csr<<<(N + 3) / 4, 256, 0, stream>>>(row_ptr, sorted_sp, Wh, out, N);
}

// Round 5
// 316.349 us; speedup vs baseline: 4.9328x; 1.0146x over previous
//
#include <hip/hip_runtime.h>
#include <hip/hip_bf16.h>

#define DOUT 64
#define DIN 128
#define NEG_SLOPE 0.2f
#define EPSV 1e-10f
#define LDA 136        // 128 + 8 bf16 pad
#define BKT_SHIFT 9    // 512 targets per coarse bucket
#define BKT_SIZE 512
#define PASSA_CHUNK 3072
#define CAP 32         // staging slots per bucket per block

typedef __attribute__((ext_vector_type(8))) __bf16 bf16x8;
typedef __attribute__((ext_vector_type(8))) unsigned short ushortx8;
typedef __attribute__((ext_vector_type(4))) float floatx4;

__device__ __forceinline__ unsigned short f32_to_bf16_rne(float f) {
    unsigned int u = __float_as_uint(f);
    u += 0x7fffu + ((u >> 16) & 1u);
    return (unsigned short)(u >> 16);
}
__device__ __forceinline__ float bf16_to_f32(unsigned short u) {
    return __uint_as_float(((unsigned int)u) << 16);
}

// ---------------------------------------------------------------------------
// Kernel 1: Wh = x @ W via bf16 MFMA; fused s_src, s_tgt. Wh stored bf16.
// ---------------------------------------------------------------------------
__global__ __launch_bounds__(256) void gat_gemm_scores(
    const float* __restrict__ x, const float* __restrict__ W,
    const float* __restrict__ a, unsigned short* __restrict__ Wh,
    float* __restrict__ ssrc, float* __restrict__ stgt, int N)
{
    __shared__ unsigned short A_sh[64 * LDA];
    __shared__ unsigned short B_sh[64 * LDA];

    const int tid = threadIdx.x;
    const int rowbase = blockIdx.x * 64;

    for (int idx = tid; idx < DIN * DOUT; idx += 256) {
        int k = idx >> 6, n = idx & 63;
        B_sh[n * LDA + k] = f32_to_bf16_rne(W[idx]);
    }
    for (int it = 0; it < 8; ++it) {
        int flat = it * 1024 + tid * 4;
        int row = flat >> 7, k = flat & 127;
        int grow = rowbase + row;
        float4 v = make_float4(0.f, 0.f, 0.f, 0.f);
        if (grow < N) v = *(const float4*)&x[(size_t)grow * DIN + k];
        ushort4 u;
        u.x = f32_to_bf16_rne(v.x); u.y = f32_to_bf16_rne(v.y);
        u.z = f32_to_bf16_rne(v.z); u.w = f32_to_bf16_rne(v.w);
        *(ushort4*)&A_sh[row * LDA + k] = u;
    }
    __syncthreads();

    const int lane = tid & 63;
    const int wv   = tid >> 6;
    const int c16  = lane & 15;
    const int quad = lane >> 4;

    floatx4 acc[4] = {floatx4{0,0,0,0}, floatx4{0,0,0,0},
                      floatx4{0,0,0,0}, floatx4{0,0,0,0}};

    const int arow = (wv * 16 + c16) * LDA;
    #pragma unroll
    for (int kk = 0; kk < 4; ++kk) {
        const int koff = kk * 32 + quad * 8;
        bf16x8 af = __builtin_bit_cast(bf16x8, *(const ushortx8*)&A_sh[arow + koff]);
        #pragma unroll
        for (int nt = 0; nt < 4; ++nt) {
            bf16x8 bf = __builtin_bit_cast(bf16x8,
                           *(const ushortx8*)&B_sh[(nt * 16 + c16) * LDA + koff]);
            acc[nt] = __builtin_amdgcn_mfma_f32_16x16x32_bf16(af, bf, acc[nt], 0, 0, 0);
        }
    }

    float asrc_v[4], atgt_v[4];
    #pragma unroll
    for (int nt = 0; nt < 4; ++nt) {
        asrc_v[nt] = a[nt * 16 + c16];
        atgt_v[nt] = a[64 + nt * 16 + c16];
    }
    const int rbase = rowbase + wv * 16 + quad * 4;
    #pragma unroll
    for (int r = 0; r < 4; ++r) {
        int row = rbase + r;
        if (row < N) {
            #pragma unroll
            for (int nt = 0; nt < 4; ++nt)
                Wh[(size_t)row * DOUT + nt * 16 + c16] = f32_to_bf16_rne(acc[nt][r]);
        }
    }
    #pragma unroll
    for (int r = 0; r < 4; ++r) {
        float ps = 0.f, pt = 0.f;
        #pragma unroll
        for (int nt = 0; nt < 4; ++nt) {
            ps += acc[nt][r] * asrc_v[nt];
            pt += acc[nt][r] * atgt_v[nt];
        }
        #pragma unroll
        for (int m = 1; m < 16; m <<= 1) {
            ps += __shfl_xor(ps, m);
            pt += __shfl_xor(pt, m);
        }
        if (c16 == 0) {
            int row = rbase + r;
            if (row < N) { ssrc[row] = ps; stgt[row] = pt; }
        }
    }
}

// ---------------------------------------------------------------------------
// Kernel 2: histogram of targets, 4 edges per thread.
// ---------------------------------------------------------------------------
__global__ __launch_bounds__(256) void gat_hist(
    const int* __restrict__ ei, int* __restrict__ cnt, int E)
{
    int e4 = (blockIdx.x * 256 + threadIdx.x) * 4;
    if (e4 + 3 < E) {
        int4 t = *(const int4*)&ei[E + e4];
        atomicAdd(&cnt[t.x], 1);
        atomicAdd(&cnt[t.y], 1);
        atomicAdd(&cnt[t.z], 1);
        atomicAdd(&cnt[t.w], 1);
    } else {
        for (int e = e4; e < E; ++e) atomicAdd(&cnt[ei[E + e]], 1);
    }
}

// ---------------------------------------------------------------------------
// Kernels 3-5: exclusive scan of cnt[N] -> row_ptr[N+1], cur copy, and
// per-bucket base cursors bcur[b] = row_ptr[b*512].
// ---------------------------------------------------------------------------
__global__ __launch_bounds__(256) void gat_scan_part(
    const int* __restrict__ cnt, int* __restrict__ bsum, int N)
{
    __shared__ int lds[256];
    int base = blockIdx.x * 1024 + threadIdx.x * 4;
    int s = 0;
    #pragma unroll
    for (int j = 0; j < 4; ++j) { int g = base + j; s += (g < N) ? cnt[g] : 0; }
    lds[threadIdx.x] = s; __syncthreads();
    for (int off = 128; off > 0; off >>= 1) {
        if (threadIdx.x < off) lds[threadIdx.x] += lds[threadIdx.x + off];
        __syncthreads();
    }
    if (threadIdx.x == 0) bsum[blockIdx.x] = lds[0];
}

__global__ __launch_bounds__(256) void gat_scan_mid(
    const int* __restrict__ bsum, int* __restrict__ bscan, int nb)
{
    __shared__ int lds[256];
    int i = threadIdx.x;
    if (i < nb) lds[i] = bsum[i];
    __syncthreads();
    if (i == 0) {
        int acc = 0;
        for (int j = 0; j < nb; ++j) { int c = lds[j]; lds[j] = acc; acc += c; }
    }
    __syncthreads();
    if (i < nb) bscan[i] = lds[i];
}

__global__ __launch_bounds__(256) void gat_scan_add(
    const int* __restrict__ cnt, const int* __restrict__ bscan,
    int* __restrict__ row_ptr, int* __restrict__ cur, int* __restrict__ bcur,
    int N, int E)
{
    __shared__ int lds[256];
    int base = blockIdx.x * 1024 + threadIdx.x * 4;
    int c[4]; int s = 0;
    #pragma unroll
    for (int j = 0; j < 4; ++j) { int g = base + j; c[j] = (g < N) ? cnt[g] : 0; s += c[j]; }
    lds[threadIdx.x] = s; __syncthreads();
    for (int off = 1; off < 256; off <<= 1) {
        int t = 0;
        if (threadIdx.x >= off) t = lds[threadIdx.x - off];
        __syncthreads();
        lds[threadIdx.x] += t;
        __syncthreads();
    }
    int run = bscan[blockIdx.x] + lds[threadIdx.x] - s;  // exclusive prefix
    #pragma unroll
    for (int j = 0; j < 4; ++j) {
        int g = base + j;
        if (g < N) {
            row_ptr[g] = run; cur[g] = run;
            if ((g & (BKT_SIZE - 1)) == 0) bcur[g >> BKT_SHIFT] = run;
        }
        run += c[j];
    }
    if (blockIdx.x == 0 && threadIdx.x == 0) row_ptr[N] = E;
}

// ---------------------------------------------------------------------------
// Kernel 6a (pass A): LDS-binned coarse scatter. Records {src|t_low<<17, p}
// binned by bucket b = t>>9 into LDS (cap 32/bucket), flushed as contiguous
// runs at atomicAdd(bcur[b], run) -> mostly full-line writes.
// ---------------------------------------------------------------------------
__global__ __launch_bounds__(256) void gat_binA(
    const int* __restrict__ ei, const float* __restrict__ ew,
    const float* __restrict__ ssrc, const float* __restrict__ stgt,
    int* __restrict__ bcur, int2* __restrict__ staged_g, int E)
{
    __shared__ int2 staged[256 * CAP];   // 64 KB
    __shared__ int fill[256];
    __shared__ int gpos[256];
    const int tid = threadIdx.x;
    fill[tid] = 0;
    __syncthreads();

    const int base = blockIdx.x * PASSA_CHUNK;
    #pragma unroll
    for (int j = 0; j < PASSA_CHUNK / 256; ++j) {
        int e = base + j * 256 + tid;
        if (e < E) {
            int s = ei[e];
            int t = ei[E + e];
            float v = ssrc[s] + stgt[t];
            v = (v > 0.f) ? v : NEG_SLOPE * v;
            v *= ew[e];
            float p = __expf(v);
            int b = t >> BKT_SHIFT;
            int2 rec = make_int2(s | ((t & (BKT_SIZE - 1)) << 17), __float_as_int(p));
            int pos = atomicAdd(&fill[b], 1);
            if (pos < CAP) {
                staged[b * CAP + pos] = rec;
            } else {                       // rare overflow: direct store
                int d = atomicAdd(&bcur[b], 1);
                staged_g[d] = rec;
            }
        }
    }
    __syncthreads();

    int f = min(fill[tid], CAP);
    gpos[tid] = (f > 0) ? atomicAdd(&bcur[tid], f) : 0;
    __syncthreads();

    for (int i = tid; i < 256 * CAP; i += 256) {
        int b = i >> 5;            // CAP == 32
        int r = i & (CAP - 1);
        if (r < min(fill[b], CAP))
            staged_g[gpos[b] + r] = staged[i];
    }
}

// ---------------------------------------------------------------------------
// Kernel 6b (pass B): fine scatter within a bucket. One block per bucket;
// all writes land in the bucket's contiguous ~65 KB window of sorted_sp,
// assembled in one XCD's L2 -> full-line writebacks.
// ---------------------------------------------------------------------------
__global__ __launch_bounds__(256) void gat_binB(
    const int2* __restrict__ staged_g, const int* __restrict__ row_ptr,
    int* __restrict__ cur, int2* __restrict__ sorted_sp, int N)
{
    const int b = blockIdx.x;
    const int tbase = b << BKT_SHIFT;
    int tend = tbase + BKT_SIZE; if (tend > N) tend = N;
    const int beg = row_ptr[tbase];
    const int end = row_ptr[tend];
    for (int i = beg + threadIdx.x; i < end; i += 256) {
        int2 rec = staged_g[i];
        int s = rec.x & 0x1FFFF;
        int t = tbase + ((rec.x >> 17) & (BKT_SIZE - 1));
        int pos = atomicAdd(&cur[t], 1);
        sorted_sp[pos] = make_int2(s, rec.y);
    }
}

// ---------------------------------------------------------------------------
// Kernel 7: segmented reduction (unchanged from R4).
// ---------------------------------------------------------------------------
__global__ __launch_bounds__(256) void gat_aggregate_csr(
    const int* __restrict__ row_ptr, const int2* __restrict__ sorted_sp,
    const unsigned short* __restrict__ Wh, float* __restrict__ out, int N)
{
    int t = blockIdx.x * 4 + (threadIdx.x >> 6);
    if (t >= N) return;
    int lane = threadIdx.x & 63;
    int sub  = lane >> 4;
    int c16  = lane & 15;

    int beg = row_ptr[t], end = row_ptr[t + 1];

    float a0 = 0.f, a1 = 0.f, a2 = 0.f, a3 = 0.f, psum = 0.f;

    int i = beg + sub;
    for (; i + 4 < end; i += 8) {
        int2 spA = sorted_sp[i];
        int2 spB = sorted_sp[i + 4];
        float pA = __int_as_float(spA.y);
        float pB = __int_as_float(spB.y);
        ushort4 wA = *(const ushort4*)&Wh[(size_t)spA.x * DOUT + c16 * 4];
        ushort4 wB = *(const ushort4*)&Wh[(size_t)spB.x * DOUT + c16 * 4];
        a0 += pA * bf16_to_f32(wA.x); a1 += pA * bf16_to_f32(wA.y);
        a2 += pA * bf16_to_f32(wA.z); a3 += pA * bf16_to_f32(wA.w);
        psum += pA;
        a0 += pB * bf16_to_f32(wB.x); a1 += pB * bf16_to_f32(wB.y);
        a2 += pB * bf16_to_f32(wB.z); a3 += pB * bf16_to_f32(wB.w);
        psum += pB;
    }
    if (i < end) {
        int2 sp = sorted_sp[i];
        float p = __int_as_float(sp.y);
        ushort4 w = *(const ushort4*)&Wh[(size_t)sp.x * DOUT + c16 * 4];
        a0 += p * bf16_to_f32(w.x); a1 += p * bf16_to_f32(w.y);
        a2 += p * bf16_to_f32(w.z); a3 += p * bf16_to_f32(w.w);
        psum += p;
    }

    #pragma unroll
    for (int m = 16; m < 64; m <<= 1) {
        a0 += __shfl_xor(a0, m);
        a1 += __shfl_xor(a1, m);
        a2 += __shfl_xor(a2, m);
        a3 += __shfl_xor(a3, m);
        psum += __shfl_xor(psum, m);
    }

    if (sub == 0) {
        float inv = 1.0f / (psum + EPSV);
        float4 o = make_float4(a0 * inv, a1 * inv, a2 * inv, a3 * inv);
        *(float4*)&out[(size_t)t * DOUT + c16 * 4] = o;
    }
}

extern "C" void kernel_launch(void* const* d_in, const int* in_sizes, int n_in,
                              void* d_out, int out_size, void* d_ws, size_t ws_size,
                              hipStream_t stream) {
    const float* x  = (const float*)d_in[0];
    const int*   ei = (const int*)d_in[1];
    const float* ew = (const float*)d_in[2];
    const float* W  = (const float*)d_in[3];
    const float* a  = (const float*)d_in[4];
    const int N = in_sizes[0] / DIN;
    const int E = in_sizes[2];
    float* out = (float*)d_out;

    // Workspace: Wh[N*64] bf16 | ssrc[N] | stgt[N] | cnt[N] | row_ptr[N+1] |
    // cur[N] | bsum[256] | bscan[256] | bcur[256] | staged_g[E] int2 | sorted_sp[E] int2
    char* wsb = (char*)d_ws;
    unsigned short* Wh = (unsigned short*)wsb;      wsb += (size_t)N * DOUT * 2;
    float* ssrc      = (float*)wsb;                 wsb += (size_t)N * 4;
    float* stgt      = (float*)wsb;                 wsb += (size_t)N * 4;
    int*   cnt       = (int*)wsb;                   wsb += (size_t)N * 4;
    int*   row_ptr   = (int*)wsb;                   wsb += (size_t)(N + 1) * 4;
    int*   cur       = (int*)wsb;                   wsb += (size_t)N * 4;
    int*   bsum      = (int*)wsb;                   wsb += 256 * 4;
    int*   bscan     = (int*)wsb;                   wsb += 256 * 4;
    int*   bcur      = (int*)wsb;                   wsb += 256 * 4;
    wsb = (char*)(((uintptr_t)wsb + 15) & ~(uintptr_t)15);
    int2*  staged_g  = (int2*)wsb;                  wsb += (size_t)E * 8;
    int2*  sorted_sp = (int2*)wsb;                  wsb += (size_t)E * 8;

    const int nb  = (N + 1023) / 1024;
    const int nbk = (N + BKT_SIZE - 1) >> BKT_SHIFT;

    hipMemsetAsync(cnt, 0, (size_t)N * sizeof(int), stream);

    gat_gemm_scores<<<(N + 63) / 64, 256, 0, stream>>>(x, W, a, Wh, ssrc, stgt, N);
    gat_hist      <<<(E / 4 + 255) / 256, 256, 0, stream>>>(ei, cnt, E);
    gat_scan_part <<<nb, 256, 0, stream>>>(cnt, bsum, N);
    gat_scan_mid  <<<1, 256, 0, stream>>>(bsum, bscan, nb);
    gat_scan_add  <<<nb, 256, 0, stream>>>(cnt, bscan, row_ptr, cur, bcur, N, E);
    gat_binA      <<<(E + PASSA_CHUNK - 1) / PASSA_CHUNK, 256, 0, stream>>>(
                      ei, ew, ssrc, stgt, bcur, staged_g, E);
    gat_binB      <<<nbk, 256, 0, stream>>>(staged_g, row_ptr, cur, sorted_sp, N);
    gat_aggregate_csr<<<(N + 3) / 4, 256, 0, stream>>>(row_ptr, sorted_sp, Wh, out, N);
}

// Round 6
// 249.306 us; speedup vs baseline: 6.2593x; 1.2689x over previous
//
#include <hip/hip_runtime.h>
#include <hip/hip_bf16.h>

#define DOUT 64
#define DIN 128
#define NEG_SLOPE 0.2f
#define EPSV 1e-10f
#define LDA 136        // 128 + 8 bf16 pad
#define BKT_SHIFT 9    // 512 targets per coarse bucket
#define BKT_SIZE 512
#define PASSA_CHUNK 3072
#define CAP 32         // staging slots per bucket per block (binA)

typedef __attribute__((ext_vector_type(8))) __bf16 bf16x8;
typedef __attribute__((ext_vector_type(8))) unsigned short ushortx8;
typedef __attribute__((ext_vector_type(4))) float floatx4;

__device__ __forceinline__ unsigned short f32_to_bf16_rne(float f) {
    unsigned int u = __float_as_uint(f);
    u += 0x7fffu + ((u >> 16) & 1u);
    return (unsigned short)(u >> 16);
}
__device__ __forceinline__ float bf16_to_f32(unsigned short u) {
    return __uint_as_float(((unsigned int)u) << 16);
}

// ---------------------------------------------------------------------------
// Kernel 1: Wh = x @ W via bf16 MFMA; fused s_src, s_tgt. Wh stored bf16.
// ---------------------------------------------------------------------------
__global__ __launch_bounds__(256) void gat_gemm_scores(
    const float* __restrict__ x, const float* __restrict__ W,
    const float* __restrict__ a, unsigned short* __restrict__ Wh,
    float* __restrict__ ssrc, float* __restrict__ stgt, int N)
{
    __shared__ unsigned short A_sh[64 * LDA];
    __shared__ unsigned short B_sh[64 * LDA];

    const int tid = threadIdx.x;
    const int rowbase = blockIdx.x * 64;

    for (int idx = tid; idx < DIN * DOUT; idx += 256) {
        int k = idx >> 6, n = idx & 63;
        B_sh[n * LDA + k] = f32_to_bf16_rne(W[idx]);
    }
    for (int it = 0; it < 8; ++it) {
        int flat = it * 1024 + tid * 4;
        int row = flat >> 7, k = flat & 127;
        int grow = rowbase + row;
        float4 v = make_float4(0.f, 0.f, 0.f, 0.f);
        if (grow < N) v = *(const float4*)&x[(size_t)grow * DIN + k];
        ushort4 u;
        u.x = f32_to_bf16_rne(v.x); u.y = f32_to_bf16_rne(v.y);
        u.z = f32_to_bf16_rne(v.z); u.w = f32_to_bf16_rne(v.w);
        *(ushort4*)&A_sh[row * LDA + k] = u;
    }
    __syncthreads();

    const int lane = tid & 63;
    const int wv   = tid >> 6;
    const int c16  = lane & 15;
    const int quad = lane >> 4;

    floatx4 acc[4] = {floatx4{0,0,0,0}, floatx4{0,0,0,0},
                      floatx4{0,0,0,0}, floatx4{0,0,0,0}};

    const int arow = (wv * 16 + c16) * LDA;
    #pragma unroll
    for (int kk = 0; kk < 4; ++kk) {
        const int koff = kk * 32 + quad * 8;
        bf16x8 af = __builtin_bit_cast(bf16x8, *(const ushortx8*)&A_sh[arow + koff]);
        #pragma unroll
        for (int nt = 0; nt < 4; ++nt) {
            bf16x8 bf = __builtin_bit_cast(bf16x8,
                           *(const ushortx8*)&B_sh[(nt * 16 + c16) * LDA + koff]);
            acc[nt] = __builtin_amdgcn_mfma_f32_16x16x32_bf16(af, bf, acc[nt], 0, 0, 0);
        }
    }

    float asrc_v[4], atgt_v[4];
    #pragma unroll
    for (int nt = 0; nt < 4; ++nt) {
        asrc_v[nt] = a[nt * 16 + c16];
        atgt_v[nt] = a[64 + nt * 16 + c16];
    }
    const int rbase = rowbase + wv * 16 + quad * 4;
    #pragma unroll
    for (int r = 0; r < 4; ++r) {
        int row = rbase + r;
        if (row < N) {
            #pragma unroll
            for (int nt = 0; nt < 4; ++nt)
                Wh[(size_t)row * DOUT + nt * 16 + c16] = f32_to_bf16_rne(acc[nt][r]);
        }
    }
    #pragma unroll
    for (int r = 0; r < 4; ++r) {
        float ps = 0.f, pt = 0.f;
        #pragma unroll
        for (int nt = 0; nt < 4; ++nt) {
            ps += acc[nt][r] * asrc_v[nt];
            pt += acc[nt][r] * atgt_v[nt];
        }
        #pragma unroll
        for (int m = 1; m < 16; m <<= 1) {
            ps += __shfl_xor(ps, m);
            pt += __shfl_xor(pt, m);
        }
        if (c16 == 0) {
            int row = rbase + r;
            if (row < N) { ssrc[row] = ps; stgt[row] = pt; }
        }
    }
}

// ---------------------------------------------------------------------------
// Kernel 2: coarse bucket histogram. LDS hist over 256 buckets per block,
// one global atomicAdd per (block,bucket) -> ~100K atomics total (vs 1.6M).
// ---------------------------------------------------------------------------
__global__ __launch_bounds__(256) void gat_bhist(
    const int* __restrict__ ei, int* __restrict__ bcnt, int E)
{
    __shared__ int lh[256];
    const int tid = threadIdx.x;
    lh[tid] = 0;
    __syncthreads();
    int base = blockIdx.x * 4096;
    #pragma unroll
    for (int j = 0; j < 4; ++j) {
        int e4 = base + j * 1024 + tid * 4;
        if (e4 + 3 < E) {
            int4 t = *(const int4*)&ei[E + e4];
            atomicAdd(&lh[t.x >> BKT_SHIFT], 1);
            atomicAdd(&lh[t.y >> BKT_SHIFT], 1);
            atomicAdd(&lh[t.z >> BKT_SHIFT], 1);
            atomicAdd(&lh[t.w >> BKT_SHIFT], 1);
        } else {
            for (int e = e4; e < E; ++e) atomicAdd(&lh[ei[E + e] >> BKT_SHIFT], 1);
        }
    }
    __syncthreads();
    if (lh[tid] > 0) atomicAdd(&bcnt[tid], lh[tid]);
}

// ---------------------------------------------------------------------------
// Kernel 3: tiny scan of 256 bucket counts -> bkt_base[257], seed bcur.
// ---------------------------------------------------------------------------
__global__ __launch_bounds__(256) void gat_bscan(
    const int* __restrict__ bcnt, int* __restrict__ bkt_base,
    int* __restrict__ bcur, int E)
{
    __shared__ int lds[256];
    int i = threadIdx.x;
    lds[i] = bcnt[i];
    __syncthreads();
    if (i == 0) {
        int acc = 0;
        for (int j = 0; j < 256; ++j) { int c = lds[j]; lds[j] = acc; acc += c; }
    }
    __syncthreads();
    bkt_base[i] = lds[i];
    bcur[i] = lds[i];
    if (i == 0) bkt_base[256] = E;
}

// ---------------------------------------------------------------------------
// Kernel 4 (pass A): LDS-binned coarse scatter. Records {src|t_low<<17, p}
// binned by bucket b = t>>9 into LDS (cap 32/bucket), flushed as contiguous
// runs at atomicAdd(bcur[b], run) -> mostly full-line writes.
// ---------------------------------------------------------------------------
__global__ __launch_bounds__(256) void gat_binA(
    const int* __restrict__ ei, const float* __restrict__ ew,
    const float* __restrict__ ssrc, const float* __restrict__ stgt,
    int* __restrict__ bcur, int2* __restrict__ staged_g, int E)
{
    __shared__ int2 staged[256 * CAP];   // 64 KB
    __shared__ int fill[256];
    __shared__ int gpos[256];
    const int tid = threadIdx.x;
    fill[tid] = 0;
    __syncthreads();

    const int base = blockIdx.x * PASSA_CHUNK;
    #pragma unroll
    for (int j = 0; j < PASSA_CHUNK / 256; ++j) {
        int e = base + j * 256 + tid;
        if (e < E) {
            int s = ei[e];
            int t = ei[E + e];
            float v = ssrc[s] + stgt[t];
            v = (v > 0.f) ? v : NEG_SLOPE * v;
            v *= ew[e];
            float p = __expf(v);
            int b = t >> BKT_SHIFT;
            int2 rec = make_int2(s | ((t & (BKT_SIZE - 1)) << 17), __float_as_int(p));
            int pos = atomicAdd(&fill[b], 1);
            if (pos < CAP) {
                staged[b * CAP + pos] = rec;
            } else {                       // rare overflow: direct store
                int d = atomicAdd(&bcur[b], 1);
                staged_g[d] = rec;
            }
        }
    }
    __syncthreads();

    int f = min(fill[tid], CAP);
    gpos[tid] = (f > 0) ? atomicAdd(&bcur[tid], f) : 0;
    __syncthreads();

    for (int i = tid; i < 256 * CAP; i += 256) {
        int b = i >> 5;            // CAP == 32
        int r = i & (CAP - 1);
        if (r < min(fill[b], CAP))
            staged_g[gpos[b] + r] = staged[i];
    }
}

// ---------------------------------------------------------------------------
// Kernel 5 (pass B): fine sort within a bucket, all in LDS. One block per
// bucket: local per-target histogram (LDS atomics), LDS exclusive scan ->
// row_ptr for this bucket's 512 targets, then place records via LDS cursors.
// No global atomics; writes confined to the bucket's contiguous window.
// ---------------------------------------------------------------------------
__global__ __launch_bounds__(256) void gat_binB(
    const int2* __restrict__ staged_g, const int* __restrict__ bkt_base,
    int* __restrict__ row_ptr, int2* __restrict__ sorted_sp, int N, int E)
{
    __shared__ int lcnt[BKT_SIZE];
    __shared__ int lcur[BKT_SIZE];
    __shared__ int lscan[256];

    const int b = blockIdx.x;
    const int tid = threadIdx.x;
    const int tbase = b << BKT_SHIFT;
    const int beg = bkt_base[b];
    const int end = bkt_base[b + 1];

    lcnt[tid] = 0; lcnt[tid + 256] = 0;
    __syncthreads();

    for (int i = beg + tid; i < end; i += 256) {
        int tl = (staged_g[i].x >> 17) & (BKT_SIZE - 1);
        atomicAdd(&lcnt[tl], 1);
    }
    __syncthreads();

    // exclusive scan over 512 counters (pairwise + Hillis-Steele over 256)
    int c0 = lcnt[2 * tid], c1 = lcnt[2 * tid + 1];
    int pair = c0 + c1;
    lscan[tid] = pair;
    __syncthreads();
    for (int off = 1; off < 256; off <<= 1) {
        int t = (tid >= off) ? lscan[tid - off] : 0;
        __syncthreads();
        lscan[tid] += t;
        __syncthreads();
    }
    int excl = lscan[tid] - pair;
    lcur[2 * tid]     = beg + excl;
    lcur[2 * tid + 1] = beg + excl + c0;
    __syncthreads();

    // write row_ptr for this bucket's targets (coalesced, contiguous)
    #pragma unroll
    for (int j = 0; j < 2; ++j) {
        int tl = tid + j * 256;
        int g = tbase + tl;
        if (g < N) row_ptr[g] = lcur[tl];
    }
    if (tid == 0 && b == gridDim.x - 1) row_ptr[N] = E;

    // place records
    for (int i = beg + tid; i < end; i += 256) {
        int2 rec = staged_g[i];
        int tl = (rec.x >> 17) & (BKT_SIZE - 1);
        int pos = atomicAdd(&lcur[tl], 1);
        sorted_sp[pos] = make_int2(rec.x & 0x1FFFF, rec.y);
    }
}

// ---------------------------------------------------------------------------
// Kernel 6: segmented reduction (unchanged from R4).
// ---------------------------------------------------------------------------
__global__ __launch_bounds__(256) void gat_aggregate_csr(
    const int* __restrict__ row_ptr, const int2* __restrict__ sorted_sp,
    const unsigned short* __restrict__ Wh, float* __restrict__ out, int N)
{
    int t = blockIdx.x * 4 + (threadIdx.x >> 6);
    if (t >= N) return;
    int lane = threadIdx.x & 63;
    int sub  = lane >> 4;
    int c16  = lane & 15;

    int beg = row_ptr[t], end = row_ptr[t + 1];

    float a0 = 0.f, a1 = 0.f, a2 = 0.f, a3 = 0.f, psum = 0.f;

    int i = beg + sub;
    for (; i + 4 < end; i += 8) {
        int2 spA = sorted_sp[i];
        int2 spB = sorted_sp[i + 4];
        float pA = __int_as_float(spA.y);
        float pB = __int_as_float(spB.y);
        ushort4 wA = *(const ushort4*)&Wh[(size_t)spA.x * DOUT + c16 * 4];
        ushort4 wB = *(const ushort4*)&Wh[(size_t)spB.x * DOUT + c16 * 4];
        a0 += pA * bf16_to_f32(wA.x); a1 += pA * bf16_to_f32(wA.y);
        a2 += pA * bf16_to_f32(wA.z); a3 += pA * bf16_to_f32(wA.w);
        psum += pA;
        a0 += pB * bf16_to_f32(wB.x); a1 += pB * bf16_to_f32(wB.y);
        a2 += pB * bf16_to_f32(wB.z); a3 += pB * bf16_to_f32(wB.w);
        psum += pB;
    }
    if (i < end) {
        int2 sp = sorted_sp[i];
        float p = __int_as_float(sp.y);
        ushort4 w = *(const ushort4*)&Wh[(size_t)sp.x * DOUT + c16 * 4];
        a0 += p * bf16_to_f32(w.x); a1 += p * bf16_to_f32(w.y);
        a2 += p * bf16_to_f32(w.z); a3 += p * bf16_to_f32(w.w);
        psum += p;
    }

    #pragma unroll
    for (int m = 16; m < 64; m <<= 1) {
        a0 += __shfl_xor(a0, m);
        a1 += __shfl_xor(a1, m);
        a2 += __shfl_xor(a2, m);
        a3 += __shfl_xor(a3, m);
        psum += __shfl_xor(psum, m);
    }

    if (sub == 0) {
        float inv = 1.0f / (psum + EPSV);
        float4 o = make_float4(a0 * inv, a1 * inv, a2 * inv, a3 * inv);
        *(float4*)&out[(size_t)t * DOUT + c16 * 4] = o;
    }
}

extern "C" void kernel_launch(void* const* d_in, const int* in_sizes, int n_in,
                              void* d_out, int out_size, void* d_ws, size_t ws_size,
                              hipStream_t stream) {
    const float* x  = (const float*)d_in[0];
    const int*   ei = (const int*)d_in[1];
    const float* ew = (const float*)d_in[2];
    const float* W  = (const float*)d_in[3];
    const float* a  = (const float*)d_in[4];
    const int N = in_sizes[0] / DIN;
    const int E = in_sizes[2];
    float* out = (float*)d_out;

    // Workspace: Wh[N*64] bf16 | ssrc[N] | stgt[N] | row_ptr[N+1] |
    // bcnt[257] | bkt_base[257] | bcur[256] | staged_g[E] int2 | sorted_sp[E] int2
    char* wsb = (char*)d_ws;
    unsigned short* Wh = (unsigned short*)wsb;      wsb += (size_t)N * DOUT * 2;
    float* ssrc      = (float*)wsb;                 wsb += (size_t)N * 4;
    float* stgt      = (float*)wsb;                 wsb += (size_t)N * 4;
    int*   row_ptr   = (int*)wsb;                   wsb += (size_t)(N + 1) * 4;
    int*   bcnt      = (int*)wsb;                   wsb += 257 * 4;
    int*   bkt_base  = (int*)wsb;                   wsb += 257 * 4;
    int*   bcur      = (int*)wsb;                   wsb += 256 * 4;
    wsb = (char*)(((uintptr_t)wsb + 15) & ~(uintptr_t)15);
    int2*  staged_g  = (int2*)wsb;                  wsb += (size_t)E * 8;
    int2*  sorted_sp = (int2*)wsb;                  wsb += (size_t)E * 8;

    const int nbk = (N + BKT_SIZE - 1) >> BKT_SHIFT;

    hipMemsetAsync(bcnt, 0, 257 * sizeof(int), stream);

    gat_gemm_scores<<<(N + 63) / 64, 256, 0, stream>>>(x, W, a, Wh, ssrc, stgt, N);
    gat_bhist <<<(E + 4095) / 4096, 256, 0, stream>>>(ei, bcnt, E);
    gat_bscan <<<1, 256, 0, stream>>>(bcnt, bkt_base, bcur, E);
    gat_binA  <<<(E + PASSA_CHUNK - 1) / PASSA_CHUNK, 256, 0, stream>>>(
                  ei, ew, ssrc, stgt, bcur, staged_g, E);
    gat_binB  <<<nbk, 256, 0, stream>>>(staged_g, bkt_base, row_ptr, sorted_sp, N, E);
    gat_aggregate_csr<<<(N + 3) / 4, 256, 0, stream>>>(row_ptr, sorted_sp, Wh, out, N);
}

// Round 8
// 240.733 us; speedup vs baseline: 6.4822x; 1.0356x over previous
//
#include <hip/hip_runtime.h>
#include <hip/hip_bf16.h>

#define DOUT 64
#define DIN 128
#define NEG_SLOPE 0.2f
#define EPSV 1e-10f
#define LDA 136        // 128 + 8 bf16 pad
#define BKT_SHIFT 9    // 512 targets per coarse bucket
#define BKT_SIZE 512
#define PASSA_CHUNK 3072
#define CAP 32         // staging slots per bucket per block (binA)

typedef __attribute__((ext_vector_type(8))) __bf16 bf16x8;
typedef __attribute__((ext_vector_type(8))) unsigned short ushortx8;
typedef __attribute__((ext_vector_type(4))) float floatx4;

__device__ __forceinline__ float bf16_to_f32(unsigned short u) {
    return __uint_as_float(((unsigned int)u) << 16);
}
__device__ __forceinline__ unsigned short f32_to_bf16(float f) {
    __hip_bfloat16 h = __float2bfloat16(f);
    unsigned short u;
    __builtin_memcpy(&u, &h, 2);
    return u;
}
__device__ __forceinline__ unsigned int f32x2_to_bf16x2(float a, float b) {
    __hip_bfloat162 h = __float22bfloat162_rn(make_float2(a, b));
    unsigned int u;
    __builtin_memcpy(&u, &h, 4);
    return u;
}

// ---------------------------------------------------------------------------
// Kernel 1: Wh = x @ W via bf16 MFMA; fused s_src, s_tgt. Wh stored bf16.
// Staging uses packed v_cvt_pk_bf16_f32 via __float22bfloat162_rn.
// ---------------------------------------------------------------------------
__global__ __launch_bounds__(256) void gat_gemm_scores(
    const float* __restrict__ x, const float* __restrict__ W,
    const float* __restrict__ a, unsigned short* __restrict__ Wh,
    float* __restrict__ ssrc, float* __restrict__ stgt, int N)
{
    __shared__ unsigned short A_sh[64 * LDA];
    __shared__ unsigned short B_sh[64 * LDA];

    const int tid = threadIdx.x;
    const int rowbase = blockIdx.x * 64;

    for (int idx = tid; idx < DIN * DOUT; idx += 256) {
        int k = idx >> 6, n = idx & 63;
        B_sh[n * LDA + k] = f32_to_bf16(W[idx]);
    }
    for (int it = 0; it < 8; ++it) {
        int flat = it * 1024 + tid * 4;
        int row = flat >> 7, k = flat & 127;
        int grow = rowbase + row;
        float4 v = make_float4(0.f, 0.f, 0.f, 0.f);
        if (grow < N) v = *(const float4*)&x[(size_t)grow * DIN + k];
        uint2 packed = make_uint2(f32x2_to_bf16x2(v.x, v.y),
                                  f32x2_to_bf16x2(v.z, v.w));
        *(uint2*)&A_sh[row * LDA + k] = packed;
    }
    __syncthreads();

    const int lane = tid & 63;
    const int wv   = tid >> 6;
    const int c16  = lane & 15;
    const int quad = lane >> 4;

    floatx4 acc[4] = {floatx4{0,0,0,0}, floatx4{0,0,0,0},
                      floatx4{0,0,0,0}, floatx4{0,0,0,0}};

    const int arow = (wv * 16 + c16) * LDA;
    #pragma unroll
    for (int kk = 0; kk < 4; ++kk) {
        const int koff = kk * 32 + quad * 8;
        bf16x8 af = __builtin_bit_cast(bf16x8, *(const ushortx8*)&A_sh[arow + koff]);
        #pragma unroll
        for (int nt = 0; nt < 4; ++nt) {
            bf16x8 bf = __builtin_bit_cast(bf16x8,
                           *(const ushortx8*)&B_sh[(nt * 16 + c16) * LDA + koff]);
            acc[nt] = __builtin_amdgcn_mfma_f32_16x16x32_bf16(af, bf, acc[nt], 0, 0, 0);
        }
    }

    float asrc_v[4], atgt_v[4];
    #pragma unroll
    for (int nt = 0; nt < 4; ++nt) {
        asrc_v[nt] = a[nt * 16 + c16];
        atgt_v[nt] = a[64 + nt * 16 + c16];
    }
    const int rbase = rowbase + wv * 16 + quad * 4;
    #pragma unroll
    for (int r = 0; r < 4; ++r) {
        int row = rbase + r;
        if (row < N) {
            #pragma unroll
            for (int nt = 0; nt < 4; ++nt)
                Wh[(size_t)row * DOUT + nt * 16 + c16] = f32_to_bf16(acc[nt][r]);
        }
    }
    #pragma unroll
    for (int r = 0; r < 4; ++r) {
        float ps = 0.f, pt = 0.f;
        #pragma unroll
        for (int nt = 0; nt < 4; ++nt) {
            ps += acc[nt][r] * asrc_v[nt];
            pt += acc[nt][r] * atgt_v[nt];
        }
        #pragma unroll
        for (int m = 1; m < 16; m <<= 1) {
            ps += __shfl_xor(ps, m);
            pt += __shfl_xor(pt, m);
        }
        if (c16 == 0) {
            int row = rbase + r;
            if (row < N) { ssrc[row] = ps; stgt[row] = pt; }
        }
    }
}

// ---------------------------------------------------------------------------
// Kernel 2: coarse bucket histogram (LDS hist, 1 global atomic per block/bucket).
// ---------------------------------------------------------------------------
__global__ __launch_bounds__(256) void gat_bhist(
    const int* __restrict__ ei, int* __restrict__ bcnt, int E)
{
    __shared__ int lh[256];
    const int tid = threadIdx.x;
    lh[tid] = 0;
    __syncthreads();
    int base = blockIdx.x * 4096;
    #pragma unroll
    for (int j = 0; j < 4; ++j) {
        int e4 = base + j * 1024 + tid * 4;
        if (e4 + 3 < E) {
            int4 t = *(const int4*)&ei[E + e4];
            atomicAdd(&lh[t.x >> BKT_SHIFT], 1);
            atomicAdd(&lh[t.y >> BKT_SHIFT], 1);
            atomicAdd(&lh[t.z >> BKT_SHIFT], 1);
            atomicAdd(&lh[t.w >> BKT_SHIFT], 1);
        } else {
            for (int e = e4; e < E; ++e) atomicAdd(&lh[ei[E + e] >> BKT_SHIFT], 1);
        }
    }
    __syncthreads();
    if (lh[tid] > 0) atomicAdd(&bcnt[tid], lh[tid]);
}

// ---------------------------------------------------------------------------
// Kernel 3: tiny scan of 256 bucket counts -> bkt_base[257], seed bcur.
// ---------------------------------------------------------------------------
__global__ __launch_bounds__(256) void gat_bscan(
    const int* __restrict__ bcnt, int* __restrict__ bkt_base,
    int* __restrict__ bcur, int E)
{
    __shared__ int lds[256];
    int i = threadIdx.x;
    lds[i] = bcnt[i];
    __syncthreads();
    if (i == 0) {
        int acc = 0;
        for (int j = 0; j < 256; ++j) { int c = lds[j]; lds[j] = acc; acc += c; }
    }
    __syncthreads();
    bkt_base[i] = lds[i];
    bcur[i] = lds[i];
    if (i == 0) bkt_base[256] = E;
}

// ---------------------------------------------------------------------------
// Kernel 4 (pass A): LDS-binned coarse scatter, 2 edges per thread per iter.
// ---------------------------------------------------------------------------
__device__ __forceinline__ void binA_one(
    int s, int t, float w, const float* __restrict__ ssrc,
    const float* __restrict__ stgt, int* fill, int2* staged,
    int* __restrict__ bcur, int2* __restrict__ staged_g)
{
    float v = ssrc[s] + stgt[t];
    v = (v > 0.f) ? v : NEG_SLOPE * v;
    v *= w;
    float p = __expf(v);
    int b = t >> BKT_SHIFT;
    int2 rec = make_int2(s | ((t & (BKT_SIZE - 1)) << 17), __float_as_int(p));
    int pos = atomicAdd(&fill[b], 1);
    if (pos < CAP) {
        staged[b * CAP + pos] = rec;
    } else {
        int d = atomicAdd(&bcur[b], 1);
        staged_g[d] = rec;
    }
}

__global__ __launch_bounds__(256) void gat_binA(
    const int* __restrict__ ei, const float* __restrict__ ew,
    const float* __restrict__ ssrc, const float* __restrict__ stgt,
    int* __restrict__ bcur, int2* __restrict__ staged_g, int E)
{
    __shared__ int2 staged[256 * CAP];   // 64 KB
    __shared__ int fill[256];
    __shared__ int gpos[256];
    const int tid = threadIdx.x;
    fill[tid] = 0;
    __syncthreads();

    const int base = blockIdx.x * PASSA_CHUNK;
    #pragma unroll
    for (int j = 0; j < PASSA_CHUNK / 512; ++j) {
        int e2 = base + j * 512 + tid * 2;
        if (e2 + 1 < E) {
            int2 ss = *(const int2*)&ei[e2];
            int2 tt = *(const int2*)&ei[E + e2];
            float2 ww = *(const float2*)&ew[e2];
            binA_one(ss.x, tt.x, ww.x, ssrc, stgt, fill, staged, bcur, staged_g);
            binA_one(ss.y, tt.y, ww.y, ssrc, stgt, fill, staged, bcur, staged_g);
        } else {
            for (int e = e2; e < E; ++e)
                binA_one(ei[e], ei[E + e], ew[e], ssrc, stgt, fill, staged, bcur, staged_g);
        }
    }
    __syncthreads();

    int f = min(fill[tid], CAP);
    gpos[tid] = (f > 0) ? atomicAdd(&bcur[tid], f) : 0;
    __syncthreads();

    for (int i = tid; i < 256 * CAP; i += 256) {
        int b = i >> 5;            // CAP == 32
        int r = i & (CAP - 1);
        if (r < min(fill[b], CAP))
            staged_g[gpos[b] + r] = staged[i];
    }
}

// ---------------------------------------------------------------------------
// Kernel 5 (pass B): fine sort within a bucket, all in LDS.
// ---------------------------------------------------------------------------
__global__ __launch_bounds__(256) void gat_binB(
    const int2* __restrict__ staged_g, const int* __restrict__ bkt_base,
    int* __restrict__ row_ptr, int2* __restrict__ sorted_sp, int N, int E)
{
    __shared__ int lcnt[BKT_SIZE];
    __shared__ int lcur[BKT_SIZE];
    __shared__ int lscan[256];

    const int b = blockIdx.x;
    const int tid = threadIdx.x;
    const int tbase = b << BKT_SHIFT;
    const int beg = bkt_base[b];
    const int end = bkt_base[b + 1];

    lcnt[tid] = 0; lcnt[tid + 256] = 0;
    __syncthreads();

    for (int i = beg + tid; i < end; i += 256) {
        int tl = (staged_g[i].x >> 17) & (BKT_SIZE - 1);
        atomicAdd(&lcnt[tl], 1);
    }
    __syncthreads();

    int c0 = lcnt[2 * tid], c1 = lcnt[2 * tid + 1];
    int pair = c0 + c1;
    lscan[tid] = pair;
    __syncthreads();
    for (int off = 1; off < 256; off <<= 1) {
        int t = (tid >= off) ? lscan[tid - off] : 0;
        __syncthreads();
        lscan[tid] += t;
        __syncthreads();
    }
    int excl = lscan[tid] - pair;
    lcur[2 * tid]     = beg + excl;
    lcur[2 * tid + 1] = beg + excl + c0;
    __syncthreads();

    #pragma unroll
    for (int j = 0; j < 2; ++j) {
        int tl = tid + j * 256;
        int g = tbase + tl;
        if (g < N) row_ptr[g] = lcur[tl];
    }
    if (tid == 0 && b == gridDim.x - 1) row_ptr[N] = E;

    for (int i = beg + tid; i < end; i += 256) {
        int2 rec = staged_g[i];
        int tl = (rec.x >> 17) & (BKT_SIZE - 1);
        int pos = atomicAdd(&lcur[tl], 1);
        sorted_sp[pos] = make_int2(rec.x & 0x1FFFF, rec.y);
    }
}

// ---------------------------------------------------------------------------
// Kernel 6: segmented reduction. One wave per target; 8 sub-groups of 8 lanes,
// each sub owns one edge per iteration; each lane loads ushort8 (16 B) = 8
// channels, so 8 lanes cover the 128 B row.
// ---------------------------------------------------------------------------
__global__ __launch_bounds__(256) void gat_aggregate_csr(
    const int* __restrict__ row_ptr, const int2* __restrict__ sorted_sp,
    const unsigned short* __restrict__ Wh, float* __restrict__ out, int N)
{
    int t = blockIdx.x * 4 + (threadIdx.x >> 6);
    if (t >= N) return;
    int lane = threadIdx.x & 63;
    int sub  = lane >> 3;    // edge slot 0..7
    int c8   = lane & 7;     // channel block: channels c8*8 .. c8*8+7

    int beg = row_ptr[t], end = row_ptr[t + 1];

    float acc[8] = {0.f, 0.f, 0.f, 0.f, 0.f, 0.f, 0.f, 0.f};
    float psum = 0.f;

    int i = beg + sub;
    for (; i + 8 < end; i += 16) {
        int2 spA = sorted_sp[i];
        int2 spB = sorted_sp[i + 8];
        float pA = __int_as_float(spA.y);
        float pB = __int_as_float(spB.y);
        ushortx8 wA = *(const ushortx8*)&Wh[(size_t)spA.x * DOUT + c8 * 8];
        ushortx8 wB = *(const ushortx8*)&Wh[(size_t)spB.x * DOUT + c8 * 8];
        #pragma unroll
        for (int j = 0; j < 8; ++j) acc[j] += pA * bf16_to_f32(wA[j]);
        psum += pA;
        #pragma unroll
        for (int j = 0; j < 8; ++j) acc[j] += pB * bf16_to_f32(wB[j]);
        psum += pB;
    }
    if (i < end) {   // loop exit guarantees at most one edge remains per sub
        int2 sp = sorted_sp[i];
        float p = __int_as_float(sp.y);
        ushortx8 w = *(const ushortx8*)&Wh[(size_t)sp.x * DOUT + c8 * 8];
        #pragma unroll
        for (int j = 0; j < 8; ++j) acc[j] += p * bf16_to_f32(w[j]);
        psum += p;
    }

    // combine the 8 edge-groups (lanes with equal c8 across subs)
    #pragma unroll
    for (int m = 8; m < 64; m <<= 1) {
        #pragma unroll
        for (int j = 0; j < 8; ++j) acc[j] += __shfl_xor(acc[j], m);
        psum += __shfl_xor(psum, m);
    }

    if (sub == 0) {
        float inv = 1.0f / (psum + EPSV);
        float4 o0 = make_float4(acc[0] * inv, acc[1] * inv, acc[2] * inv, acc[3] * inv);
        float4 o1 = make_float4(acc[4] * inv, acc[5] * inv, acc[6] * inv, acc[7] * inv);
        *(float4*)&out[(size_t)t * DOUT + c8 * 8]     = o0;
        *(float4*)&out[(size_t)t * DOUT + c8 * 8 + 4] = o1;
    }
}

extern "C" void kernel_launch(void* const* d_in, const int* in_sizes, int n_in,
                              void* d_out, int out_size, void* d_ws, size_t ws_size,
                              hipStream_t stream) {
    const float* x  = (const float*)d_in[0];
    const int*   ei = (const int*)d_in[1];
    const float* ew = (const float*)d_in[2];
    const float* W  = (const float*)d_in[3];
    const float* a  = (const float*)d_in[4];
    const int N = in_sizes[0] / DIN;
    const int E = in_sizes[2];
    float* out = (float*)d_out;

    char* wsb = (char*)d_ws;
    unsigned short* Wh = (unsigned short*)wsb;      wsb += (size_t)N * DOUT * 2;
    float* ssrc      = (float*)wsb;                 wsb += (size_t)N * 4;
    float* stgt      = (float*)wsb;                 wsb += (size_t)N * 4;
    int*   row_ptr   = (int*)wsb;                   wsb += (size_t)(N + 1) * 4;
    int*   bcnt      = (int*)wsb;                   wsb += 257 * 4;
    int*   bkt_base  = (int*)wsb;                   wsb += 257 * 4;
    int*   bcur      = (int*)wsb;                   wsb += 256 * 4;
    wsb = (char*)(((uintptr_t)wsb + 15) & ~(uintptr_t)15);
    int2*  staged_g  = (int2*)wsb;                  wsb += (size_t)E * 8;
    int2*  sorted_sp = (int2*)wsb;                  wsb += (size_t)E * 8;

    const int nbk = (N + BKT_SIZE - 1) >> BKT_SHIFT;

    (void)hipMemsetAsync(bcnt, 0, 257 * sizeof(int), stream);

    gat_gemm_scores<<<(N + 63) / 64, 256, 0, stream>>>(x, W, a, Wh, ssrc, stgt, N);
    gat_bhist <<<(E + 4095) / 4096, 256, 0, stream>>>(ei, bcnt, E);
    gat_bscan <<<1, 256, 0, stream>>>(bcnt, bkt_base, bcur, E);
    gat_binA  <<<(E + PASSA_CHUNK - 1) / PASSA_CHUNK, 256, 0, stream>>>(
                  ei, ew, ssrc, stgt, bcur, staged_g, E);
    gat_binB  <<<nbk, 256, 0, stream>>>(staged_g, bkt_base, row_ptr, sorted_sp, N, E);
    gat_aggregate_csr<<<(N + 3) / 4, 256, 0, stream>>>(row_ptr, sorted_sp, Wh, out, N);
}